// Round 2
// baseline (133.116 us; speedup 1.0000x reference)
//
#include <hip/hip_runtime.h>
#include <hip/hip_bf16.h>

// LSTM_71382356459716 R10: occupancy 4->8 waves/SIMD.
// R9 counters: VALUBusy 58%, MfmaUtil 15.7%, Occupancy 30%, HBM 5.8% -> the
// kernel is latency-bound: per-SIMD issue work ~2.2-2.5k cyc/step vs 4.95k
// wall. 4 waves/SIMD can't cover the MFMA->activation->LDS->barrier chain.
// Changes vs R8:
//  (1) 512-thread blocks, 8 waves x 2 M-tiles (was 4 x 4). Same total work,
//      same 1024 blocks -> 32 waves/CU = 8/SIMD (max). waves_per_eu(8,8),
//      per-wave A-frags 24 VGPR (was 48) so 64-VGPR budget holds.
//  (2) exp2 weight folding: prep scales W/bias by -log2e (i,f,o) and
//      -2*log2e (g) so activation uses bare v_exp_f32 (exp2) -- saves 4
//      v_mul per unit, algebraically exact.
//  (3) h-store: unit 8w+4i+q stored at col 8w+2q+i (W_hh cols permuted in
//      prep to match; FC epilogue maps back) -> one ds_write_b32 per lane
//      instead of scattered b16 stores. 2-way bank aliasing only (free).
// Kept: 16 rows/block, bias folded as W col 28 vs constant-1, balanced
// stagers (lanes 0..13 of each wave), two-deep x prefetch, double-buffered
// LDS rows of 104 shorts, 3 conflict-free ds_read_b128 B-frags, 1
// barrier/step.

namespace {
constexpr int B_TOT   = 16384;
constexpr int T_STEPS = 28;
constexpr int IN_DIM  = 28;
constexpr int HID     = 64;
constexpr int OUT_DIM = 10;
constexpr int ROWS    = 16;    // batch rows per block -> 1024 blocks, 4/CU
constexpr int THREADS = 512;   // 8 waves
constexpr int KP      = 104;   // row stride in shorts (208 B, odd*16B)
constexpr int XROW    = T_STEPS * IN_DIM;  // 784 floats per batch row
constexpr int NFRAG   = 16 * 3;            // 16 Mtiles * 3 kchunks
constexpr int WS_ELEMS = NFRAG * 64 * 8;   // 24576 bf16 = 48 KB
}

typedef __attribute__((ext_vector_type(8))) short short8v;   // 8 bf16
typedef __attribute__((ext_vector_type(4))) short short4v;
typedef __attribute__((ext_vector_type(4))) float float4v;

__device__ __forceinline__ short f2bf_cold(float f) {
  union { float f; unsigned u; } v; v.f = f;
  unsigned r = v.u + 0x7FFFu + ((v.u >> 16) & 1u);
  return (short)(r >> 16);
}
__device__ __forceinline__ float bf2f(short s) {
  union { unsigned u; float f; } v; v.u = ((unsigned)(unsigned short)s) << 16;
  return v.f;
}
__device__ __forceinline__ unsigned pk2(float a, float b) {  // 2xf32->bf16x2
  __hip_bfloat162 h = __float22bfloat162_rn(float2{a, b});
  union { __hip_bfloat162 h; unsigned u; } cv; cv.h = h; return cv.u;
}

// ---- setup: permute weights+bias into MFMA A-frag order (runs every call) --
// ws layout: frag f = mt*3 + kc, lane l, elem j:
//   ws[(f*64 + l)*8 + j] = bf16 of A[m=16*mt+(l&15)][k=kc*32+(l>>4)*8+j]
// gate row g = (m&3)*64 + (m>>2); k<28 -> W_ih, k==28 -> b_ih+b_hh,
// 29..31 -> 0, k>=32 -> W_hh[:, u(k-32)] where stored col c holds unit
// u(c) = 8*(c>>3) + 4*(c&1) + ((c>>1)&3)  (h-store permutation).
// All values pre-scaled by -log2(e) (gates i,f,o) / -2*log2(e) (gate g) so
// the main kernel uses bare exp2.
__global__ void lstm_prep(const float* __restrict__ W_ih,
                          const float* __restrict__ W_hh,
                          const float* __restrict__ b_ih,
                          const float* __restrict__ b_hh,
                          unsigned short* __restrict__ ws) {
  int idx = blockIdx.x * blockDim.x + threadIdx.x;
  if (idx >= WS_ELEMS) return;
  int j  = idx & 7;
  int l  = (idx >> 3) & 63;
  int fk = idx >> 9;            // mt*3 + kc
  int kc = fk % 3;
  int mt = fk / 3;
  int m  = 16 * mt + (l & 15);
  int unit = m >> 2, type = m & 3;
  int g  = type * 64 + unit;
  int k  = kc * 32 + (l >> 4) * 8 + j;
  float v = 0.0f;
  if (k < IN_DIM)        v = W_ih[g * IN_DIM + k];
  else if (k == IN_DIM)  v = b_ih[g] + b_hh[g];
  else if (k >= 32) {
    int c = k - 32;
    int u = 8 * (c >> 3) + 4 * (c & 1) + ((c >> 1) & 3);
    v = W_hh[g * HID + u];
  }
  // fold exp argument scaling into the weights (type 2 == gate g -> tanh)
  v *= (type == 2) ? -2.8853900817779268f : -1.4426950408889634f;
  ws[idx] = (unsigned short)f2bf_cold(v);
}

__global__ __attribute__((amdgpu_flat_work_group_size(THREADS, THREADS),
                          amdgpu_waves_per_eu(8, 8)))
void lstm_mfma8(const float* __restrict__ x,
                const unsigned short* __restrict__ wfrag,
                const float* __restrict__ W_fc,
                const float* __restrict__ b_fc, float* __restrict__ out) {
  __shared__ short hs[2][ROWS][KP];   // [buf][row][k]: 0..27 x, 28 = 1.0, 32..95 h

  const int tid  = threadIdx.x;
  const int lane = tid & 63;
  const int w    = tid >> 6;      // wave 0..7 -> units 8w..8w+7
  const int l15  = lane & 15;
  const int q    = lane >> 4;     // 0..3
  const int b0   = blockIdx.x * ROWS;

  // ---- stationary A: 6 coalesced 16B loads per lane (frag-order from ws) --
  short8v a[2][3];
#pragma unroll
  for (int i = 0; i < 2; ++i)
#pragma unroll
    for (int kc = 0; kc < 3; ++kc)
      a[i][kc] = *(const short8v*)&wfrag[((((2 * w + i) * 3) + kc) * 64 + lane) * 8];

  // zero both buffers, then set the constant bias column (never overwritten)
  for (int idx = tid; idx < 2 * ROWS * KP; idx += THREADS) (&hs[0][0][0])[idx] = 0;
  __syncthreads();
  if (tid < 2 * ROWS) hs[tid >> 4][tid & 15][IN_DIM] = (short)0x3F80;  // bf16 1.0

  // ---- x staging balanced across waves: lanes 0..13 of each wave -----------
  const bool stager = (lane < 14);
  const int  s  = w * 14 + lane;         // 0..111 = 16 rows x 7 float4 groups
  const int  sr = s / 7;
  const int  sc = s - 7 * sr;
  const float* xptr = x + (size_t)(b0 + sr) * XROW + sc * 4;

  // stage x_0 directly; preload x_1 into the in-flight register
  float4 xfly = {0.f, 0.f, 0.f, 0.f};
  if (stager) {
    float4 x0 = *(const float4*)xptr;
    short4v sv;
    unsigned plo = pk2(x0.x, x0.y), phi = pk2(x0.z, x0.w);
    sv[0] = (short)(plo & 0xFFFF); sv[1] = (short)(plo >> 16);
    sv[2] = (short)(phi & 0xFFFF); sv[3] = (short)(phi >> 16);
    *(short4v*)&hs[0][sr][sc * 4] = sv;
    xfly = *(const float4*)(xptr + 1 * IN_DIM);   // x_1, consumed at t=0
  }
  __syncthreads();

  float c_state[2] = {0.f, 0.f};

  for (int t = 0; t < T_STEPS; ++t) {
    const int cur = t & 1, nxt = cur ^ 1;

    // B-frags: lane holds B[k = kc*32 + q*8 + j][n = l15]
    short8v bf0 = *(const short8v*)&hs[cur][l15][q * 8];
    short8v bf1 = *(const short8v*)&hs[cur][l15][32 + q * 8];
    short8v bf2 = *(const short8v*)&hs[cur][l15][64 + q * 8];

    // store x_{t+1} (loaded a full step ago), issue load of x_{t+2}
    if (stager) {
      if (t + 1 < T_STEPS) {
        short4v sv;
        unsigned plo = pk2(xfly.x, xfly.y), phi = pk2(xfly.z, xfly.w);
        sv[0] = (short)(plo & 0xFFFF); sv[1] = (short)(plo >> 16);
        sv[2] = (short)(phi & 0xFFFF); sv[3] = (short)(phi >> 16);
        *(short4v*)&hs[nxt][sr][sc * 4] = sv;
      }
      if (t + 2 < T_STEPS)
        xfly = *(const float4*)(xptr + (t + 2) * IN_DIM);
    }

    const float4v zero4 = {0.f, 0.f, 0.f, 0.f};
    float4v acc[2];
#pragma unroll
    for (int i = 0; i < 2; ++i)
      acc[i] = __builtin_amdgcn_mfma_f32_16x16x32_bf16(a[i][0], bf0, zero4, 0, 0, 0);
#pragma unroll
    for (int i = 0; i < 2; ++i)
      acc[i] = __builtin_amdgcn_mfma_f32_16x16x32_bf16(a[i][1], bf1, acc[i], 0, 0, 0);
#pragma unroll
    for (int i = 0; i < 2; ++i)
      acc[i] = __builtin_amdgcn_mfma_f32_16x16x32_bf16(a[i][2], bf2, acc[i], 0, 0, 0);

    // activations; exp-scales pre-folded into A so these are bare exp2.
    // lane-local: acc[i] regs 0..3 = (i,f,g,o) of unit 8w+4i+q, row l15.
    float hv[2];
#pragma unroll
    for (int i = 0; i < 2; ++i) {
      float4v g4 = acc[i];
      float Ei = __builtin_amdgcn_exp2f(g4[0]);
      float Ef = __builtin_amdgcn_exp2f(g4[1]);
      float Eg = __builtin_amdgcn_exp2f(g4[2]);
      float Eo = __builtin_amdgcn_exp2f(g4[3]);
      float di = 1.0f + Ei, df = 1.0f + Ef;
      float r1 = __builtin_amdgcn_rcpf(di * df);
      float iv = r1 * df;
      float fv = r1 * di;
      float gv = fmaf(2.0f, __builtin_amdgcn_rcpf(1.0f + Eg), -1.0f);
      float cn = fmaf(fv, c_state[i], iv * gv);
      c_state[i] = cn;
      float ct = fminf(fmaxf(cn, -15.0f), 15.0f);   // tanh saturated beyond
      float Ec = __builtin_amdgcn_exp2f(-2.8853900817779268f * ct);
      float dn = 1.0f + Eo, dc = 1.0f + Ec;
      float r2 = __builtin_amdgcn_rcpf(dn * dc);
      float ov = r2 * dc;
      float tc = fmaf(2.0f * r2, dn, -1.0f);
      hv[i] = ov * tc;
    }
    // packed bf16 convert; unit 8w+4i+q lands at col 8w+2q+i -> single b32
    unsigned p01 = pk2(hv[0], hv[1]);
    *(unsigned*)&hs[nxt][l15][32 + 8 * w + 2 * q] = p01;

    __syncthreads();
  }

  // ---- FC epilogue: final h in hs[0] (t=27 wrote nxt = 0), cols 32..95 -----
  // stored col c holds unit u(c) = 8*(c>>3) + 4*(c&1) + ((c>>1)&3)
  if (tid < ROWS * OUT_DIM) {           // 160 outputs
    const int r = tid / OUT_DIM;
    const int o = tid - r * OUT_DIM;
    float sacc = b_fc[o];
#pragma unroll
    for (int c = 0; c < HID; ++c) {
      int u = 8 * (c >> 3) + 4 * (c & 1) + ((c >> 1) & 3);
      sacc += bf2f(hs[0][r][32 + c]) * W_fc[o * HID + u];
    }
    out[(b0 + r) * OUT_DIM + o] = sacc;
  }
}

extern "C" void kernel_launch(void* const* d_in, const int* in_sizes, int n_in,
                              void* d_out, int out_size, void* d_ws, size_t ws_size,
                              hipStream_t stream) {
  const float* x    = (const float*)d_in[0];
  const float* W_ih = (const float*)d_in[1];
  const float* W_hh = (const float*)d_in[2];
  const float* b_ih = (const float*)d_in[3];
  const float* b_hh = (const float*)d_in[4];
  const float* W_fc = (const float*)d_in[5];
  const float* b_fc = (const float*)d_in[6];
  float* out = (float*)d_out;
  unsigned short* ws = (unsigned short*)d_ws;   // 48 KB frag-ordered weights

  lstm_prep<<<(WS_ELEMS + 255) / 256, 256, 0, stream>>>(W_ih, W_hh, b_ih, b_hh, ws);

  dim3 grid(B_TOT / ROWS);   // 1024 blocks -> 4 blocks/CU co-resident
  dim3 block(THREADS);
  lstm_mfma8<<<grid, block, 0, stream>>>(x, ws, W_fc, b_fc, out);
}